// Round 1
// baseline (227.644 us; speedup 1.0000x reference)
//
#include <hip/hip_runtime.h>

#define THREADS 256

// In-register 16-point unnormalized FWHT (fully unrolled -> stays in VGPRs).
__device__ __forceinline__ void fwht16(float v[16]) {
#pragma unroll
  for (int h = 1; h < 16; h <<= 1) {
#pragma unroll
    for (int i = 0; i < 16; i += 2 * h) {
#pragma unroll
      for (int j = i; j < i + h; ++j) {
        float a = v[j], b = v[j + h];
        v[j]     = a + b;
        v[j + h] = a - b;
      }
    }
  }
}

// LDS address swizzle: +4 words of pad per 64-word block.
// Keeps float4 (16B) alignment for contiguous 4-word groups whose base is
// a multiple of 4 within a 64-block, and rotates banks so the strided
// (stride-4 and stride-64 word) transpose reads are at worst 2-way aliased
// (free on gfx950).
__device__ __forceinline__ int pad(int i) { return i + ((i >> 6) << 2); }

__global__ __launch_bounds__(THREADS, 4) void hadamard4096_kernel(
    const float* __restrict__ in, float* __restrict__ out) {
  // 4096 data words + 4 pad words per 64 -> 4352 words = 17408 B
  __shared__ __align__(16) float lds[4096 + 256];

  const int t = threadIdx.x;
  const int row = blockIdx.x;
  const float4* in4 = reinterpret_cast<const float4*>(in + (size_t)row * 4096);

  // ---- Load: coalesced float4. Thread t holds elements
  //      idx = kk*1024 + 4t + jj  (bits {11:10}=kk, {9:2}=t, {1:0}=jj)
  float v[16];
#pragma unroll
  for (int kk = 0; kk < 4; ++kk) {
    float4 a = in4[kk * 256 + t];
    v[kk * 4 + 0] = a.x;
    v[kk * 4 + 1] = a.y;
    v[kk * 4 + 2] = a.z;
    v[kk * 4 + 3] = a.w;
  }

  // ---- Phase 1: H16 over element bits {11,10,1,0} (register index m)
  fwht16(v);

  // ---- Transpose 1 write: per kk a contiguous 4-word group -> ds_write_b128
#pragma unroll
  for (int kk = 0; kk < 4; ++kk) {
    int idx = kk * 1024 + 4 * t;
    *reinterpret_cast<float4*>(&lds[pad(idx)]) =
        make_float4(v[kk * 4 + 0], v[kk * 4 + 1], v[kk * 4 + 2], v[kk * 4 + 3]);
  }
  __syncthreads();

  // ---- Transpose 1 read: thread u=(kk,ss,jj) gathers q=0..15
  //      idx = kk*1024 + ss*64 + 4q + jj
  const int kk = t >> 6;
  const int ss = (t >> 2) & 15;
  const int jj = t & 3;
  const int base1 = kk * 1024 + ss * 64 + jj;
  float z[16];
#pragma unroll
  for (int q = 0; q < 16; ++q) {
    z[q] = lds[pad(base1 + 4 * q)];
  }

  // ---- Phase 2: H16 over element bits {5:2}
  fwht16(z);

  // ---- Transpose 2 write: same addresses this thread read (self-owned,
  //      no barrier needed between the read above and this write)
#pragma unroll
  for (int q = 0; q < 16; ++q) {
    lds[pad(base1 + 4 * q)] = z[q];
  }
  __syncthreads();

  // ---- Transpose 2 read: thread w=(kk,qq,jj) gathers s=0..15
  //      idx = kk*1024 + s*64 + 4*qq + jj
  const int qq = (t >> 2) & 15;
  const int base2 = kk * 1024 + 4 * qq + jj;
  float y[16];
#pragma unroll
  for (int s = 0; s < 16; ++s) {
    y[s] = lds[pad(base2 + 64 * s)];
  }

  // ---- Phase 3: H16 over element bits {9:6}
  fwht16(y);

  // ---- Store: scaled by 1/sqrt(4096)=1/64. Per s: lanes write 256
  //      consecutive bytes -> coalesced dword stores.
  float* op = out + (size_t)row * 4096 + kk * 1024 + (t & 63);
#pragma unroll
  for (int s = 0; s < 16; ++s) {
    op[64 * s] = y[s] * 0.015625f;
  }
}

extern "C" void kernel_launch(void* const* d_in, const int* in_sizes, int n_in,
                              void* d_out, int out_size, void* d_ws, size_t ws_size,
                              hipStream_t stream) {
  const float* x = (const float*)d_in[0];
  float* out = (float*)d_out;
  const int rows = in_sizes[0] >> 12;  // 8192 rows of 4096
  hipLaunchKernelGGL(hadamard4096_kernel, dim3(rows), dim3(THREADS), 0, stream,
                     x, out);
}

// Round 2
// 227.634 us; speedup vs baseline: 1.0000x; 1.0000x over previous
//
#include <hip/hip_runtime.h>

#define THREADS 256

// Radix-4 in-place unnormalized WHT on 4 values.
__device__ __forceinline__ void fwht4(float& a, float& b, float& c, float& d) {
  float s0 = a + b, d0 = a - b, s1 = c + d, d1 = c - d;
  a = s0 + s1; b = d0 + d1; c = s0 - s1; d = d0 - d1;
}

// 16-point in-place WHT over v[0..15] (H16 = H4 (x) H4, order-independent).
__device__ __forceinline__ void fwht16(float v[16]) {
#pragma unroll
  for (int j = 0; j < 4; ++j) fwht4(v[j * 4 + 0], v[j * 4 + 1], v[j * 4 + 2], v[j * 4 + 3]);
#pragma unroll
  for (int j = 0; j < 4; ++j) fwht4(v[0 + j], v[4 + j], v[8 + j], v[12 + j]);
}

// LDS swizzle: logical word i -> i + 4*(i>>6). All transpose access patterns
// are <=2-way bank-aliased (free on gfx950, m136), and any 16B-aligned run of
// 4 words within a 64-block stays contiguous (ds_*_b128 legal).
__device__ __forceinline__ int pad(int i) { return i + ((i >> 6) << 2); }

__global__ __launch_bounds__(THREADS, 8) void hadamard4096_kernel(
    const float* __restrict__ in, float* __restrict__ out) {
  // 4096 data words + 4 pad words per 64 -> 17408 B; 8 blocks/CU = 139 KB LDS.
  __shared__ __align__(16) float lds[4096 + 256];

  const int t = threadIdx.x;
  const int row = blockIdx.x;
  const float4* in4 = reinterpret_cast<const float4*>(in + (size_t)row * 4096);

  // Single register tile reused by all three phases (anti-spill).
  float v[16];

  // ---- Load + phase-1a: per-float4 radix-4 over bits {1:0} as each load
  //      lands (staged vmcnt). Thread t holds idx = kk*1024 + 4t + jj.
  float4 a0 = in4[0 * 256 + t];
  float4 a1 = in4[1 * 256 + t];
  float4 a2 = in4[2 * 256 + t];
  float4 a3 = in4[3 * 256 + t];
  v[0] = a0.x; v[1] = a0.y; v[2] = a0.z; v[3] = a0.w;
  fwht4(v[0], v[1], v[2], v[3]);
  v[4] = a1.x; v[5] = a1.y; v[6] = a1.z; v[7] = a1.w;
  fwht4(v[4], v[5], v[6], v[7]);
  v[8] = a2.x; v[9] = a2.y; v[10] = a2.z; v[11] = a2.w;
  fwht4(v[8], v[9], v[10], v[11]);
  v[12] = a3.x; v[13] = a3.y; v[14] = a3.z; v[15] = a3.w;
  fwht4(v[12], v[13], v[14], v[15]);

  // ---- Phase-1b: radix-4 over bits {11:10} (the kk register dimension).
#pragma unroll
  for (int j = 0; j < 4; ++j) fwht4(v[0 + j], v[4 + j], v[8 + j], v[12 + j]);

  // ---- Transpose-1 write: contiguous 4-word groups -> ds_write_b128.
#pragma unroll
  for (int kk = 0; kk < 4; ++kk) {
    *reinterpret_cast<float4*>(&lds[pad(kk * 1024 + 4 * t)]) =
        make_float4(v[kk * 4 + 0], v[kk * 4 + 1], v[kk * 4 + 2], v[kk * 4 + 3]);
  }
  __syncthreads();

  // ---- Transpose-1 read: thread (kk,ss,jj) gathers q=0..15 at
  //      idx = kk*1024 + ss*64 + 4q + jj; padded base + 16B offsets.
  const int kk = t >> 6;
  const int ss = (t >> 2) & 15;
  const int jj = t & 3;
  const int a1base = kk * 1024 + ss * 64 + jj + 4 * (kk * 16 + ss);  // pad(base1)
#pragma unroll
  for (int q = 0; q < 16; ++q) v[q] = lds[a1base + 4 * q];

  // ---- Phase 2: H16 over element bits {5:2}
  fwht16(v);

  // ---- Transpose-2 write: self-owned addresses (same as just read).
#pragma unroll
  for (int q = 0; q < 16; ++q) lds[a1base + 4 * q] = v[q];
  __syncthreads();

  // ---- Transpose-2 read: thread (kk,qq,jj) gathers s=0..15 at
  //      idx = kk*1024 + 64s + 4qq + jj; padded stride = 68 words.
  const int qq = (t >> 2) & 15;
  const int a2base = kk * 1088 + 4 * qq + jj;  // pad-folded base
#pragma unroll
  for (int s = 0; s < 16; ++s) v[s] = lds[a2base + 68 * s];

  // ---- Phase 3: H16 over element bits {9:6}, scaled by 1/sqrt(4096).
  fwht16(v);

  // ---- Store: per s, lanes cover 256 contiguous bytes (coalesced dwords).
  float* op = out + (size_t)row * 4096 + kk * 1024 + (t & 63);
#pragma unroll
  for (int s = 0; s < 16; ++s) op[64 * s] = v[s] * 0.015625f;
}

extern "C" void kernel_launch(void* const* d_in, const int* in_sizes, int n_in,
                              void* d_out, int out_size, void* d_ws, size_t ws_size,
                              hipStream_t stream) {
  const float* x = (const float*)d_in[0];
  float* out = (float*)d_out;
  const int rows = in_sizes[0] >> 12;  // 8192 rows of 4096
  hipLaunchKernelGGL(hadamard4096_kernel, dim3(rows), dim3(THREADS), 0, stream,
                     x, out);
}